// Round 9
// baseline (1007.418 us; speedup 1.0000x reference)
//
#include <hip/hip_runtime.h>
#include <hip/hip_fp16.h>

#define BB 4
#define NN 5000
#define KK 4
#define EE 80000
#define DD 512
#define LL 6
#define LMM 3

typedef _Float16 f16x8 __attribute__((ext_vector_type(8)));
typedef _Float16 f16x4 __attribute__((ext_vector_type(4)));
typedef _Float16 f16x2 __attribute__((ext_vector_type(2)));
typedef float f32x4 __attribute__((ext_vector_type(4)));

__device__ __forceinline__ void async_copy16(_Float16* lds, const _Float16* g) {
    __builtin_amdgcn_global_load_lds((const __attribute__((address_space(1))) void*)g,
                                     (__attribute__((address_space(3))) void*)lds,
                                     16, 0, 0);
}

// ---------------- CSR build ----------------
__global__ void zero_int2(int* a, int* b, int n) {
    int i = blockIdx.x * blockDim.x + threadIdx.x;
    if (i < n) { a[i] = 0; b[i] = 0; }
}

__global__ void count_deg(const int* __restrict__ dst, int* __restrict__ deg) {
    int e = blockIdx.x * blockDim.x + threadIdx.x;
    if (e < EE) atomicAdd(&deg[dst[e]], 1);
}

__global__ __launch_bounds__(1024) void scan_off(const int* __restrict__ deg, int* __restrict__ off) {
    __shared__ int s[1024];
    const int n = NN, tot = NN + 1;
    const int per = (tot + 1023) / 1024;   // 5
    int tid = threadIdx.x;
    int start = tid * per;
    int loc[8];
    int sum = 0;
    for (int i = 0; i < per; i++) {
        int idx = start + i;
        int v = (idx < n) ? deg[idx] : 0;
        loc[i] = sum; sum += v;
    }
    s[tid] = sum; __syncthreads();
    for (int o = 1; o < 1024; o <<= 1) {
        int v = (tid >= o) ? s[tid - o] : 0;
        __syncthreads();
        s[tid] += v;
        __syncthreads();
    }
    int base = (tid > 0) ? s[tid - 1] : 0;
    for (int i = 0; i < per; i++) {
        int idx = start + i;
        if (idx < tot) off[idx] = base + loc[i];
    }
}

// packed edge record: {src, weight_bits} -> one 8B wave-uniform load per edge
__global__ void scatter_edges(const int* __restrict__ src, const int* __restrict__ dst,
                              const float* __restrict__ ew, const int* __restrict__ off,
                              int* __restrict__ cursor, int2* __restrict__ epk) {
    int e = blockIdx.x * blockDim.x + threadIdx.x;
    if (e >= EE) return;
    int d = dst[e];
    int p = atomicAdd(&cursor[d], 1);
    epk[off[d] + p] = make_int2(src[e], __float_as_int(ew[e]));
}

// ---------------- embedding gather -> f16 ----------------
__global__ __launch_bounds__(256) void embed_kernel(const int* __restrict__ x_idx,
                                                    const float* __restrict__ emb,
                                                    _Float16* __restrict__ x) {
    int row = blockIdx.x;   // b*NN + n
    int d = threadIdx.x * 2;
    int4 iv = *reinterpret_cast<const int4*>(x_idx + (size_t)row * 4);
    float2 a = *reinterpret_cast<const float2*>(emb + (size_t)iv.x * DD + d);
    float2 b = *reinterpret_cast<const float2*>(emb + (size_t)iv.y * DD + d);
    float2 c = *reinterpret_cast<const float2*>(emb + (size_t)iv.z * DD + d);
    float2 e = *reinterpret_cast<const float2*>(emb + (size_t)iv.w * DD + d);
    f16x2 v;
    v[0] = (_Float16)(a.x + b.x + c.x + e.x);
    v[1] = (_Float16)(a.y + b.y + c.y + e.y);
    *reinterpret_cast<f16x2*>(x + (size_t)row * DD + d) = v;
}

// ---------------- GenConv message + softmax-agg + residual ----------------
// R7 locality + scalar edge path: wave = one (b,h,n); grid (8, NN/2) so
// bid%8 = bh pins each (b,h)'s 2.56MB gather set to one XCD's L2 (R7: FETCH
// 12.6MB, proven). Per edge: one wave-uniform 8B record load, readfirstlane
// -> SALU gather base; no LDS staging, no per-edge VALU addressing, no
// two-level loop. Compiler pipelines the independent iterations (no manual
// pipeline - R3 lesson). exp without max-shift (messages small); +1e-7
// restored after the ratio (exact: eps cancels in alpha).
__global__ __launch_bounds__(128) void conv_kernel(const _Float16* __restrict__ x,
                                                   const int2* __restrict__ epk,
                                                   const int* __restrict__ off,
                                                   _Float16* __restrict__ t) {
    int bh = blockIdx.x;                 // b*2 + h
    int b = bh >> 1, h = bh & 1;
    int wave = threadIdx.x >> 6, lane = threadIdx.x & 63;
    int n = blockIdx.y * 2 + wave;
    const _Float16* xb = x + (size_t)b * NN * DD + h * (DD / 2);
    int e0 = off[n], e1 = off[n + 1];
    int num = e1 - e0;
    const int2* ep = epk + e0;
    int d0 = lane * 4;
    float S[4] = {0.f, 0.f, 0.f, 0.f};
    float Z[4] = {0.f, 0.f, 0.f, 0.f};
    for (int j = 0; j < num; j++) {
        int2 e = ep[j];                   // wave-uniform address -> broadcast
        int sj = __builtin_amdgcn_readfirstlane(e.x);
        float w = __uint_as_float(__builtin_amdgcn_readfirstlane((unsigned)e.y));
        f16x4 xv = *reinterpret_cast<const f16x4*>(xb + (size_t)sj * DD + d0);
#pragma unroll
        for (int q = 0; q < 4; q++) {
            float m = fmaxf((float)xv[q] + w, 0.f);
            float p = __expf(m);
            S[q] += p;
            Z[q] = fmaf(m, p, Z[q]);
        }
    }
    f16x4 xn = *reinterpret_cast<const f16x4*>(xb + (size_t)n * DD + d0);
    f16x4 o;
#pragma unroll
    for (int q = 0; q < 4; q++) {
        float agg = (num > 0) ? (Z[q] / (S[q] + 1e-16f) + 1e-7f) : 0.f;
        o[q] = (_Float16)(agg + (float)xn[q]);
    }
    *reinterpret_cast<f16x4*>(t + ((size_t)b * NN + n) * DD + h * (DD / 2) + d0) = o;
}

// ---------------- weight transpose f32 -> f16 (N-major), all layers per launch --------
__global__ void transpose_f32_f16(const float* __restrict__ W, _Float16* __restrict__ Wt,
                                  int K, int Nc) {
    __shared__ float tile[32][33];
    size_t loff = (size_t)blockIdx.z * K * Nc;
    int n0 = blockIdx.x * 32, k0 = blockIdx.y * 32;
    int tx = threadIdx.x, ty = threadIdx.y;
    for (int i = 0; i < 32; i += 8)
        tile[ty + i][tx] = W[loff + (size_t)(k0 + ty + i) * Nc + n0 + tx];
    __syncthreads();
    for (int i = 0; i < 32; i += 8)
        Wt[loff + (size_t)(n0 + ty + i) * K + k0 + tx] = (_Float16)tile[tx][ty + i];
}

// ---------------- MFMA GEMM: C = A(MxK) * Bt(NxK)^T ----------------
// BK=32 double-buffered global_load_lds, one barrier per K-iter. XCD-major
// block mapping: bid%8 = m-tile%8 (A m-stripe L2-resident per XCD). LDS chunk
// swizzle (col ^= row&3) breaks 64B-row-stride bank aliasing. m-tiles padded
// to x8: excess blocks load clamped rows, store nothing.
// MODE 0: bn+relu  1: bias+relu  2: bias+gelu  (-> f16)
template <int MODE>
__global__ __launch_bounds__(256) void gemm_kernel(const _Float16* __restrict__ A,
                                                   const _Float16* __restrict__ Bt,
                                                   const float* __restrict__ bias,
                                                   const float* __restrict__ g,
                                                   const float* __restrict__ be,
                                                   _Float16* __restrict__ Cout,
                                                   int M, int N, int K, int nt) {
    constexpr int BM = 128, BN = 128, BK = 32;
    constexpr int BUF = (BM + BN) * BK;           // elements per buffer
    __shared__ __align__(16) _Float16 smem[2 * BUF];  // 32 KB
    int tid = threadIdx.x;
    int bid = blockIdx.x;
    int xcd = bid & 7, gidx = bid >> 3;
    int m0 = (xcd + 8 * (gidx / nt)) * BM;
    int n0 = (gidx % nt) * BN;
    int lane = tid & 63, wave = tid >> 6;
    int wm = (wave & 1) * 64, wn = (wave >> 1) * 64;
    int l16 = lane & 15, quad = lane >> 4;
    // staging: row r = tid>>2 (and +64), chunk col c = tid&3, swizzled c^(r&3)
    int r0 = tid >> 2, r1 = r0 + 64;
    int c0s = ((tid & 3) ^ (r0 & 3)) * 8;
    int c1s = ((tid & 3) ^ (r1 & 3)) * 8;
    const _Float16* pa0 = A + (size_t)min(m0 + r0, M - 1) * K + c0s;
    const _Float16* pa1 = A + (size_t)min(m0 + r1, M - 1) * K + c1s;
    const _Float16* pb0 = Bt + (size_t)(n0 + r0) * K + c0s;
    const _Float16* pb1 = Bt + (size_t)(n0 + r1) * K + c1s;
    int la0 = tid * 8, la1 = (tid + 256) * 8;     // A slot offsets within buffer
    int lb0 = BM * BK + la0, lb1 = BM * BK + la1; // B slot offsets within buffer

    f32x4 acc[4][4] = {};
    // prologue: stage tile 0 into buffer 0
    async_copy16(smem + la0, pa0);
    async_copy16(smem + la1, pa1);
    async_copy16(smem + lb0, pb0);
    async_copy16(smem + lb1, pb1);
    int buf = 0;
    int qa = (quad ^ (l16 & 3)) * 8;              // de-swizzled chunk offset
    for (int k0 = 0; k0 < K; k0 += BK, buf ^= BUF) {
        __syncthreads();                       // drains buf loads; frees other buffer
        int kn = k0 + BK;
        int nb = buf ^ BUF;
        if (kn < K) {                          // issue next tile AFTER the barrier
            async_copy16(smem + nb + la0, pa0 + kn);
            async_copy16(smem + nb + la1, pa1 + kn);
            async_copy16(smem + nb + lb0, pb0 + kn);
            async_copy16(smem + nb + lb1, pb1 + kn);
        }
        f16x8 af[4], bf[4];
#pragma unroll
        for (int i = 0; i < 4; i++)
            af[i] = *reinterpret_cast<const f16x8*>(&smem[buf + (wm + i * 16 + l16) * BK + qa]);
#pragma unroll
        for (int j = 0; j < 4; j++)
            bf[j] = *reinterpret_cast<const f16x8*>(&smem[buf + BM * BK + (wn + j * 16 + l16) * BK + qa]);
#pragma unroll
        for (int i = 0; i < 4; i++)
#pragma unroll
            for (int j = 0; j < 4; j++)
                acc[i][j] = __builtin_amdgcn_mfma_f32_16x16x32_f16(af[i], bf[j], acc[i][j], 0, 0, 0);
    }
    __syncthreads();
    // epilogue: per 64-col phase, owning waves write Ct[128][64] to LDS, then
    // all 256 threads store f16x8 full sectors (no write-allocate RFO)
    const float invs = rsqrtf(1.0f + 1e-5f);
    _Float16* Ct = smem;
#pragma unroll
    for (int p = 0; p < 2; p++) {
        if ((wave >> 1) == p) {
#pragma unroll
            for (int i = 0; i < 4; i++) {
#pragma unroll
                for (int j = 0; j < 4; j++) {
                    int col = n0 + wn + j * 16 + l16;
#pragma unroll
                    for (int r = 0; r < 4; r++) {
                        float v = acc[i][j][r] + bias[col];
                        if (MODE == 0) {
                            v = fmaxf(v * (g[col] * invs) + be[col], 0.f);
                        } else if (MODE == 1) {
                            v = fmaxf(v, 0.f);
                        } else {
                            v = 0.5f * v * (1.0f + erff(v * 0.70710678118654752f));
                        }
                        Ct[(wm + i * 16 + quad * 4 + r) * 64 + j * 16 + l16] = (_Float16)v;
                    }
                }
            }
        }
        __syncthreads();
#pragma unroll
        for (int k = 0; k < 4; k++) {
            int ch = tid + 256 * k;
            int row = ch >> 3, cc = (ch & 7) * 8;
            int grow = m0 + row;
            if (grow < M)
                *reinterpret_cast<f16x8*>(Cout + (size_t)grow * N + n0 + p * 64 + cc) =
                    *reinterpret_cast<const f16x8*>(&Ct[row * 64 + cc]);
        }
        __syncthreads();
    }
}

// ---------------- LayerNorm (f16 in/out) ----------------
__device__ __forceinline__ float block_sum_256(float v, volatile float* sbuf) {
    __syncthreads();
    for (int s = 32; s; s >>= 1) v += __shfl_down(v, s);
    int wv = threadIdx.x >> 6, ln = threadIdx.x & 63;
    if (ln == 0) sbuf[wv] = v;
    __syncthreads();
    if (threadIdx.x == 0) sbuf[4] = sbuf[0] + sbuf[1] + sbuf[2] + sbuf[3];
    __syncthreads();
    return sbuf[4];
}

__global__ __launch_bounds__(256) void ln_kernel(const _Float16* __restrict__ x,
                                                 const float* __restrict__ lg,
                                                 const float* __restrict__ lb,
                                                 _Float16* __restrict__ t) {
    __shared__ float sbuf[5];
    size_t row = blockIdx.x;
    int d = threadIdx.x * 2;
    f16x2 xv = *reinterpret_cast<const f16x2*>(x + row * DD + d);
    float v0 = (float)xv[0], v1 = (float)xv[1];
    float mu = block_sum_256(v0 + v1, sbuf) * (1.0f / DD);
    float d0 = v0 - mu, d1 = v1 - mu;
    float var = block_sum_256(d0 * d0 + d1 * d1, sbuf) * (1.0f / DD);
    float rs = rsqrtf(var + 1e-5f);
    f16x2 o;
    o[0] = (_Float16)(d0 * rs * lg[d] + lb[d]);
    o[1] = (_Float16)(d1 * rs * lg[d + 1] + lb[d + 1]);
    *reinterpret_cast<f16x2*>(t + row * DD + d) = o;
}

// ---------------- final projection + mean ----------------
__global__ void init_out(float* out, const float* __restrict__ bout) {
    if (threadIdx.x < BB) out[threadIdx.x] = bout[0];
}

__global__ __launch_bounds__(256) void final_reduce(const _Float16* __restrict__ h,
                                                    const float* __restrict__ wout,
                                                    float* __restrict__ out) {
    int b = blockIdx.y;
    const _Float16* hb = h + (size_t)b * NN * DD;
    int lane = threadIdx.x & 63, wave = threadIdx.x >> 6;
    float wv[8];
#pragma unroll
    for (int j = 0; j < 8; j++) wv[j] = wout[lane * 8 + j];
    float acc = 0.f;
    for (int n = blockIdx.x * 4 + wave; n < NN; n += gridDim.x * 4) {
        f16x8 hv = *reinterpret_cast<const f16x8*>(hb + (size_t)n * DD + lane * 8);
#pragma unroll
        for (int j = 0; j < 8; j++) acc += (float)hv[j] * wv[j];
    }
    for (int s = 32; s; s >>= 1) acc += __shfl_down(acc, s);
    __shared__ float sb[4];
    if (lane == 0) sb[wave] = acc;
    __syncthreads();
    if (threadIdx.x == 0) atomicAdd(&out[b], (sb[0] + sb[1] + sb[2] + sb[3]) * (1.0f / NN));
}

extern "C" void kernel_launch(void* const* d_in, const int* in_sizes, int n_in,
                              void* d_out, int out_size, void* d_ws, size_t ws_size,
                              hipStream_t stream) {
    const int*   x_idx = (const int*)d_in[0];
    const int*   eidx  = (const int*)d_in[1];
    const float* ew    = (const float*)d_in[2];
    const float* emb   = (const float*)d_in[3];
    const float* W1    = (const float*)d_in[4];
    const float* b1    = (const float*)d_in[5];
    const float* g1    = (const float*)d_in[6];
    const float* be1   = (const float*)d_in[7];
    const float* W2    = (const float*)d_in[8];
    const float* b2    = (const float*)d_in[9];
    const float* lng   = (const float*)d_in[10];
    const float* lnb   = (const float*)d_in[11];
    const float* Wm    = (const float*)d_in[12];
    const float* bm    = (const float*)d_in[13];
    const float* Wout  = (const float*)d_in[14];
    const float* bout  = (const float*)d_in[15];
    float* out = (float*)d_out;

    char* w = (char*)d_ws;
    size_t o = 0;
    auto alloc = [&](size_t bytes) -> void* {
        void* p = w + o;
        o = (o + bytes + 255) & ~(size_t)255;
        return p;
    };
    _Float16*  x    = (_Float16*)alloc((size_t)BB * NN * DD * 2);
    _Float16*  t    = (_Float16*)alloc((size_t)BB * NN * DD * 2);
    _Float16*  h    = (_Float16*)alloc((size_t)BB * NN * 2 * DD * 2);
    _Float16*  W1t  = (_Float16*)alloc((size_t)LL * 2 * DD * DD * 2);
    _Float16*  W2t  = (_Float16*)alloc((size_t)LL * DD * 2 * DD * 2);
    _Float16*  Wmt  = (_Float16*)alloc((size_t)LMM * DD * DD * 2);
    int*    deg    = (int*)alloc((size_t)NN * 4);
    int*    offs   = (int*)alloc((size_t)(NN + 1) * 4);
    int*    cursor = (int*)alloc((size_t)NN * 4);
    int2*   epk    = (int2*)alloc((size_t)EE * 8);

    const int* src = eidx;
    const int* dst = eidx + EE;

    zero_int2<<<(NN + 255) / 256, 256, 0, stream>>>(deg, cursor, NN);
    count_deg<<<(EE + 255) / 256, 256, 0, stream>>>(dst, deg);
    scan_off<<<1, 1024, 0, stream>>>(deg, offs);
    scatter_edges<<<(EE + 255) / 256, 256, 0, stream>>>(src, dst, ew, offs, cursor, epk);
    embed_kernel<<<BB * NN, 256, 0, stream>>>(x_idx, emb, x);

    transpose_f32_f16<<<dim3(2 * DD / 32, DD / 32, LL), dim3(32, 8), 0, stream>>>(W1, W1t, DD, 2 * DD);
    transpose_f32_f16<<<dim3(DD / 32, 2 * DD / 32, LL), dim3(32, 8), 0, stream>>>(W2, W2t, 2 * DD, DD);
    transpose_f32_f16<<<dim3(DD / 32, DD / 32, LMM), dim3(32, 8), 0, stream>>>(Wm, Wmt, DD, DD);

    const int M = BB * NN;
    const int mt8 = ((M + 127) / 128 + 7) & ~7;   // m-tiles padded to multiple of 8 (160)
    for (int l = 0; l < LL; l++) {
        conv_kernel<<<dim3(2 * BB, NN / 2), 128, 0, stream>>>(x, epk, offs, t);
        gemm_kernel<0><<<mt8 * 8, 256, 0, stream>>>(
            t, W1t + (size_t)l * 2 * DD * DD, b1 + (size_t)l * 2 * DD,
            g1 + (size_t)l * 2 * DD, be1 + (size_t)l * 2 * DD, h, M, 2 * DD, DD, 8);
        gemm_kernel<1><<<mt8 * 4, 256, 0, stream>>>(
            h, W2t + (size_t)l * DD * 2 * DD, b2 + (size_t)l * DD,
            nullptr, nullptr, x, M, DD, 2 * DD, 4);
    }
    ln_kernel<<<M, 256, 0, stream>>>(x, lng, lnb, t);
    gemm_kernel<2><<<mt8 * 4, 256, 0, stream>>>(
        t, Wmt, bm, nullptr, nullptr, h, M, DD, DD, 4);
    gemm_kernel<2><<<mt8 * 4, 256, 0, stream>>>(
        h, Wmt + (size_t)DD * DD, bm + DD, nullptr, nullptr, t, M, DD, DD, 4);
    gemm_kernel<2><<<mt8 * 4, 256, 0, stream>>>(
        t, Wmt + (size_t)2 * DD * DD, bm + 2 * DD, nullptr, nullptr, h, M, DD, DD, 4);
    init_out<<<1, 64, 0, stream>>>(out, bout);
    final_reduce<<<dim3(32, BB), 256, 0, stream>>>(h, Wout, out);
}

// Round 10
// 940.336 us; speedup vs baseline: 1.0713x; 1.0713x over previous
//
#include <hip/hip_runtime.h>
#include <hip/hip_fp16.h>

#define BB 4
#define NN 5000
#define KK 4
#define EE 80000
#define DD 512
#define LL 6
#define LMM 3

typedef _Float16 f16x8 __attribute__((ext_vector_type(8)));
typedef _Float16 f16x4 __attribute__((ext_vector_type(4)));
typedef _Float16 f16x2 __attribute__((ext_vector_type(2)));
typedef float f32x4 __attribute__((ext_vector_type(4)));

__device__ __forceinline__ void async_copy16(_Float16* lds, const _Float16* g) {
    __builtin_amdgcn_global_load_lds((const __attribute__((address_space(1))) void*)g,
                                     (__attribute__((address_space(3))) void*)lds,
                                     16, 0, 0);
}

// ---------------- CSR build ----------------
__global__ void zero_int2(int* a, int* b, int n) {
    int i = blockIdx.x * blockDim.x + threadIdx.x;
    if (i < n) { a[i] = 0; b[i] = 0; }
}

__global__ void count_deg(const int* __restrict__ dst, int* __restrict__ deg) {
    int e = blockIdx.x * blockDim.x + threadIdx.x;
    if (e < EE) atomicAdd(&deg[dst[e]], 1);
}

__global__ __launch_bounds__(1024) void scan_off(const int* __restrict__ deg, int* __restrict__ off) {
    __shared__ int s[1024];
    const int n = NN, tot = NN + 1;
    const int per = (tot + 1023) / 1024;   // 5
    int tid = threadIdx.x;
    int start = tid * per;
    int loc[8];
    int sum = 0;
    for (int i = 0; i < per; i++) {
        int idx = start + i;
        int v = (idx < n) ? deg[idx] : 0;
        loc[i] = sum; sum += v;
    }
    s[tid] = sum; __syncthreads();
    for (int o = 1; o < 1024; o <<= 1) {
        int v = (tid >= o) ? s[tid - o] : 0;
        __syncthreads();
        s[tid] += v;
        __syncthreads();
    }
    int base = (tid > 0) ? s[tid - 1] : 0;
    for (int i = 0; i < per; i++) {
        int idx = start + i;
        if (idx < tot) off[idx] = base + loc[i];
    }
}

__global__ void scatter_edges(const int* __restrict__ src, const int* __restrict__ dst,
                              const float* __restrict__ ew, const int* __restrict__ off,
                              int* __restrict__ cursor, int* __restrict__ srcs, float* __restrict__ wss) {
    int e = blockIdx.x * blockDim.x + threadIdx.x;
    if (e >= EE) return;
    int d = dst[e];
    int p = atomicAdd(&cursor[d], 1);
    int idx = off[d] + p;
    srcs[idx] = src[e];
    wss[idx] = ew[e];
}

// ---------------- embedding gather -> f16 ----------------
__global__ __launch_bounds__(256) void embed_kernel(const int* __restrict__ x_idx,
                                                    const float* __restrict__ emb,
                                                    _Float16* __restrict__ x) {
    int row = blockIdx.x;   // b*NN + n
    int d = threadIdx.x * 2;
    int4 iv = *reinterpret_cast<const int4*>(x_idx + (size_t)row * 4);
    float2 a = *reinterpret_cast<const float2*>(emb + (size_t)iv.x * DD + d);
    float2 b = *reinterpret_cast<const float2*>(emb + (size_t)iv.y * DD + d);
    float2 c = *reinterpret_cast<const float2*>(emb + (size_t)iv.z * DD + d);
    float2 e = *reinterpret_cast<const float2*>(emb + (size_t)iv.w * DD + d);
    f16x2 v;
    v[0] = (_Float16)(a.x + b.x + c.x + e.x);
    v[1] = (_Float16)(a.y + b.y + c.y + e.y);
    *reinterpret_cast<f16x2*>(x + (size_t)row * DD + d) = v;
}

// ---------------- GenConv message + softmax-agg + residual ----------------
// EXACT R7 structure (empirical best, 50us): feature-split XCD pinning
// (bid%8 = b*2+h -> 2.56MB gather set per XCD, L2-resident; FETCH 12.6MB
// proven), LDS-staged 64-edge chunks + plain inner loop (compiler keeps
// gathers in flight). R3/R8/R9 restructurings all regressed - do not touch.
__global__ __launch_bounds__(128) void conv_kernel(const _Float16* __restrict__ x,
                                                   const int* __restrict__ srcs,
                                                   const float* __restrict__ wss,
                                                   const int* __restrict__ off,
                                                   _Float16* __restrict__ t) {
    int bh = blockIdx.x;                 // b*2 + h
    int b = bh >> 1, h = bh & 1;
    int wave = threadIdx.x >> 6, lane = threadIdx.x & 63;
    int n = blockIdx.y * 2 + wave;
    const _Float16* xb = x + (size_t)b * NN * DD + h * (DD / 2);
    int e0 = off[n], e1 = off[n + 1];
    __shared__ int   ss[2][64];
    __shared__ float sw[2][64];
    int d0 = lane * 4;
    float S[4] = {0.f, 0.f, 0.f, 0.f};
    float Z[4] = {0.f, 0.f, 0.f, 0.f};
    for (int base = e0; base < e1; base += 64) {
        int cnt = min(64, e1 - base);
        if (lane < cnt) { ss[wave][lane] = srcs[base + lane]; sw[wave][lane] = wss[base + lane]; }
        for (int j = 0; j < cnt; j++) {
            f16x4 xv = *reinterpret_cast<const f16x4*>(xb + (size_t)ss[wave][j] * DD + d0);
            float w = sw[wave][j];
#pragma unroll
            for (int q = 0; q < 4; q++) {
                float m = fmaxf((float)xv[q] + w, 0.f);
                float p = __expf(m);
                S[q] += p;
                Z[q] = fmaf(m, p, Z[q]);
            }
        }
    }
    f16x4 xn = *reinterpret_cast<const f16x4*>(xb + (size_t)n * DD + d0);
    f16x4 o;
#pragma unroll
    for (int q = 0; q < 4; q++) {
        float agg = (e1 > e0) ? (Z[q] / (S[q] + 1e-16f) + 1e-7f) : 0.f;
        o[q] = (_Float16)(agg + (float)xn[q]);
    }
    *reinterpret_cast<f16x4*>(t + ((size_t)b * NN + n) * DD + h * (DD / 2) + d0) = o;
}

// ---------------- weight transpose f32 -> f16 (N-major), all layers per launch --------
__global__ void transpose_f32_f16(const float* __restrict__ W, _Float16* __restrict__ Wt,
                                  int K, int Nc) {
    __shared__ float tile[32][33];
    size_t loff = (size_t)blockIdx.z * K * Nc;
    int n0 = blockIdx.x * 32, k0 = blockIdx.y * 32;
    int tx = threadIdx.x, ty = threadIdx.y;
    for (int i = 0; i < 32; i += 8)
        tile[ty + i][tx] = W[loff + (size_t)(k0 + ty + i) * Nc + n0 + tx];
    __syncthreads();
    for (int i = 0; i < 32; i += 8)
        Wt[loff + (size_t)(n0 + ty + i) * K + k0 + tx] = (_Float16)tile[tx][ty + i];
}

// ---------------- MFMA GEMM: C = A(MxK) * Bt(NxK)^T ----------------
// 256x128 tile, 512 threads (8 waves as 4m x 2n of 64x64), BK=32 dbuf
// global_load_lds, one barrier per K-iter. vs 128x128: 1.33x less staging
// traffic per FLOP, half the blocks (prologue/epilogue amortized 2x).
// LDS 48KB -> 3 blocks/CU = 24 waves/CU. XCD-major m-stripes (bid%8).
// LDS chunk swizzle (col ^= row&3). M=20480 = 80 tiles exactly.
// MODE 0: bn+relu  1: bias+relu  2: bias+gelu  (-> f16)
template <int MODE>
__global__ __launch_bounds__(512) void gemm_kernel(const _Float16* __restrict__ A,
                                                   const _Float16* __restrict__ Bt,
                                                   const float* __restrict__ bias,
                                                   const float* __restrict__ g,
                                                   const float* __restrict__ be,
                                                   _Float16* __restrict__ Cout,
                                                   int M, int N, int K, int nt) {
    constexpr int BM = 256, BN = 128, BK = 32;
    constexpr int BUF = (BM + BN) * BK;               // 12288 elems = 24 KB
    __shared__ __align__(16) _Float16 smem[2 * BUF];  // 48 KB
    int tid = threadIdx.x;
    int bid = blockIdx.x;
    int xcd = bid & 7, gidx = bid >> 3;
    int m0 = (xcd + 8 * (gidx / nt)) * BM;
    int n0 = (gidx % nt) * BN;
    int lane = tid & 63, wave = tid >> 6;
    int wm = (wave & 3) * 64, wn = (wave >> 2) * 64;
    int l16 = lane & 15, quad = lane >> 4;
    // staging: A = 1024 chunks (2/thread), B = 512 chunks (1/thread); 16B chunks
    int ra0 = tid >> 2, ra1 = ra0 + 128, rb = tid >> 2;  // rb only valid for tid<512: B rows 0..127
    int ca0 = ((tid & 3) ^ (ra0 & 3)) * 8;
    int ca1 = ((tid & 3) ^ (ra1 & 3)) * 8;
    // B handled by all 512 threads too: chunk id tid, row tid>>2 in 0..127
    int cb = ((tid & 3) ^ (rb & 3)) * 8;
    const _Float16* pa0 = A + (size_t)min(m0 + ra0, M - 1) * K + ca0;
    const _Float16* pa1 = A + (size_t)min(m0 + ra1, M - 1) * K + ca1;
    const _Float16* pb  = Bt + (size_t)(n0 + rb) * K + cb;
    int la0 = tid * 8, la1 = (tid + 512) * 8;       // A slots within buffer
    int lb  = BM * BK + tid * 8;                    // B slot within buffer

    f32x4 acc[4][4] = {};
    async_copy16(smem + la0, pa0);
    async_copy16(smem + la1, pa1);
    async_copy16(smem + lb, pb);
    int buf = 0;
    int qa = (quad ^ (l16 & 3)) * 8;                // de-swizzled chunk offset
    for (int k0 = 0; k0 < K; k0 += BK, buf ^= BUF) {
        __syncthreads();
        int kn = k0 + BK;
        int nb = buf ^ BUF;
        if (kn < K) {
            async_copy16(smem + nb + la0, pa0 + kn);
            async_copy16(smem + nb + la1, pa1 + kn);
            async_copy16(smem + nb + lb, pb + kn);
        }
        f16x8 af[4], bf[4];
#pragma unroll
        for (int i = 0; i < 4; i++)
            af[i] = *reinterpret_cast<const f16x8*>(&smem[buf + (wm + i * 16 + l16) * BK + qa]);
#pragma unroll
        for (int j = 0; j < 4; j++)
            bf[j] = *reinterpret_cast<const f16x8*>(&smem[buf + BM * BK + (wn + j * 16 + l16) * BK + qa]);
#pragma unroll
        for (int i = 0; i < 4; i++)
#pragma unroll
            for (int j = 0; j < 4; j++)
                acc[i][j] = __builtin_amdgcn_mfma_f32_16x16x32_f16(af[i], bf[j], acc[i][j], 0, 0, 0);
    }
    __syncthreads();
    // epilogue: 2 col-phases; owning waves (wn/64 == p) write Ct[256][64] to
    // LDS, then all 512 threads store f16x8 full sectors
    const float invs = rsqrtf(1.0f + 1e-5f);
    _Float16* Ct = smem;
#pragma unroll
    for (int p = 0; p < 2; p++) {
        if ((wave >> 2) == p) {
#pragma unroll
            for (int i = 0; i < 4; i++) {
#pragma unroll
                for (int j = 0; j < 4; j++) {
                    int col = n0 + wn + j * 16 + l16;
#pragma unroll
                    for (int r = 0; r < 4; r++) {
                        float v = acc[i][j][r] + bias[col];
                        if (MODE == 0) {
                            v = fmaxf(v * (g[col] * invs) + be[col], 0.f);
                        } else if (MODE == 1) {
                            v = fmaxf(v, 0.f);
                        } else {
                            v = 0.5f * v * (1.0f + erff(v * 0.70710678118654752f));
                        }
                        Ct[(wm + i * 16 + quad * 4 + r) * 64 + j * 16 + l16] = (_Float16)v;
                    }
                }
            }
        }
        __syncthreads();
#pragma unroll
        for (int k = 0; k < 4; k++) {
            int ch = tid + 512 * k;                 // 2048 chunks: 256 rows x 8
            int row = ch >> 3, cc = (ch & 7) * 8;
            int grow = m0 + row;
            if (grow < M)
                *reinterpret_cast<f16x8*>(Cout + (size_t)grow * N + n0 + p * 64 + cc) =
                    *reinterpret_cast<const f16x8*>(&Ct[row * 64 + cc]);
        }
        __syncthreads();
    }
}

// ---------------- LayerNorm (f16 in/out) ----------------
__device__ __forceinline__ float block_sum_256(float v, volatile float* sbuf) {
    __syncthreads();
    for (int s = 32; s; s >>= 1) v += __shfl_down(v, s);
    int wv = threadIdx.x >> 6, ln = threadIdx.x & 63;
    if (ln == 0) sbuf[wv] = v;
    __syncthreads();
    if (threadIdx.x == 0) sbuf[4] = sbuf[0] + sbuf[1] + sbuf[2] + sbuf[3];
    __syncthreads();
    return sbuf[4];
}

__global__ __launch_bounds__(256) void ln_kernel(const _Float16* __restrict__ x,
                                                 const float* __restrict__ lg,
                                                 const float* __restrict__ lb,
                                                 _Float16* __restrict__ t) {
    __shared__ float sbuf[5];
    size_t row = blockIdx.x;
    int d = threadIdx.x * 2;
    f16x2 xv = *reinterpret_cast<const f16x2*>(x + row * DD + d);
    float v0 = (float)xv[0], v1 = (float)xv[1];
    float mu = block_sum_256(v0 + v1, sbuf) * (1.0f / DD);
    float d0 = v0 - mu, d1 = v1 - mu;
    float var = block_sum_256(d0 * d0 + d1 * d1, sbuf) * (1.0f / DD);
    float rs = rsqrtf(var + 1e-5f);
    f16x2 o;
    o[0] = (_Float16)(d0 * rs * lg[d] + lb[d]);
    o[1] = (_Float16)(d1 * rs * lg[d + 1] + lb[d + 1]);
    *reinterpret_cast<f16x2*>(t + row * DD + d) = o;
}

// ---------------- final projection + mean ----------------
__global__ void init_out(float* out, const float* __restrict__ bout) {
    if (threadIdx.x < BB) out[threadIdx.x] = bout[0];
}

__global__ __launch_bounds__(256) void final_reduce(const _Float16* __restrict__ h,
                                                    const float* __restrict__ wout,
                                                    float* __restrict__ out) {
    int b = blockIdx.y;
    const _Float16* hb = h + (size_t)b * NN * DD;
    int lane = threadIdx.x & 63, wave = threadIdx.x >> 6;
    float wv[8];
#pragma unroll
    for (int j = 0; j < 8; j++) wv[j] = wout[lane * 8 + j];
    float acc = 0.f;
    for (int n = blockIdx.x * 4 + wave; n < NN; n += gridDim.x * 4) {
        f16x8 hv = *reinterpret_cast<const f16x8*>(hb + (size_t)n * DD + lane * 8);
#pragma unroll
        for (int j = 0; j < 8; j++) acc += (float)hv[j] * wv[j];
    }
    for (int s = 32; s; s >>= 1) acc += __shfl_down(acc, s);
    __shared__ float sb[4];
    if (lane == 0) sb[wave] = acc;
    __syncthreads();
    if (threadIdx.x == 0) atomicAdd(&out[b], (sb[0] + sb[1] + sb[2] + sb[3]) * (1.0f / NN));
}

extern "C" void kernel_launch(void* const* d_in, const int* in_sizes, int n_in,
                              void* d_out, int out_size, void* d_ws, size_t ws_size,
                              hipStream_t stream) {
    const int*   x_idx = (const int*)d_in[0];
    const int*   eidx  = (const int*)d_in[1];
    const float* ew    = (const float*)d_in[2];
    const float* emb   = (const float*)d_in[3];
    const float* W1    = (const float*)d_in[4];
    const float* b1    = (const float*)d_in[5];
    const float* g1    = (const float*)d_in[6];
    const float* be1   = (const float*)d_in[7];
    const float* W2    = (const float*)d_in[8];
    const float* b2    = (const float*)d_in[9];
    const float* lng   = (const float*)d_in[10];
    const float* lnb   = (const float*)d_in[11];
    const float* Wm    = (const float*)d_in[12];
    const float* bm    = (const float*)d_in[13];
    const float* Wout  = (const float*)d_in[14];
    const float* bout  = (const float*)d_in[15];
    float* out = (float*)d_out;

    char* w = (char*)d_ws;
    size_t o = 0;
    auto alloc = [&](size_t bytes) -> void* {
        void* p = w + o;
        o = (o + bytes + 255) & ~(size_t)255;
        return p;
    };
    _Float16*  x    = (_Float16*)alloc((size_t)BB * NN * DD * 2);
    _Float16*  t    = (_Float16*)alloc((size_t)BB * NN * DD * 2);
    _Float16*  h    = (_Float16*)alloc((size_t)BB * NN * 2 * DD * 2);
    _Float16*  W1t  = (_Float16*)alloc((size_t)LL * 2 * DD * DD * 2);
    _Float16*  W2t  = (_Float16*)alloc((size_t)LL * DD * 2 * DD * 2);
    _Float16*  Wmt  = (_Float16*)alloc((size_t)LMM * DD * DD * 2);
    int*    deg    = (int*)alloc((size_t)NN * 4);
    int*    offs   = (int*)alloc((size_t)(NN + 1) * 4);
    int*    cursor = (int*)alloc((size_t)NN * 4);
    int*    srcs   = (int*)alloc((size_t)EE * 4);
    float*  wss    = (float*)alloc((size_t)EE * 4);

    const int* src = eidx;
    const int* dst = eidx + EE;

    zero_int2<<<(NN + 255) / 256, 256, 0, stream>>>(deg, cursor, NN);
    count_deg<<<(EE + 255) / 256, 256, 0, stream>>>(dst, deg);
    scan_off<<<1, 1024, 0, stream>>>(deg, offs);
    scatter_edges<<<(EE + 255) / 256, 256, 0, stream>>>(src, dst, ew, offs, cursor, srcs, wss);
    embed_kernel<<<BB * NN, 256, 0, stream>>>(x_idx, emb, x);

    transpose_f32_f16<<<dim3(2 * DD / 32, DD / 32, LL), dim3(32, 8), 0, stream>>>(W1, W1t, DD, 2 * DD);
    transpose_f32_f16<<<dim3(DD / 32, 2 * DD / 32, LL), dim3(32, 8), 0, stream>>>(W2, W2t, 2 * DD, DD);
    transpose_f32_f16<<<dim3(DD / 32, DD / 32, LMM), dim3(32, 8), 0, stream>>>(Wm, Wmt, DD, DD);

    const int M = BB * NN;                    // 20480 = 80 x 256 exactly
    const int mt8 = ((M + 255) / 256 + 7) & ~7;   // 80, already multiple of 8
    for (int l = 0; l < LL; l++) {
        conv_kernel<<<dim3(2 * BB, NN / 2), 128, 0, stream>>>(x, srcs, wss, offs, t);
        gemm_kernel<0><<<mt8 * 8, 512, 0, stream>>>(
            t, W1t + (size_t)l * 2 * DD * DD, b1 + (size_t)l * 2 * DD,
            g1 + (size_t)l * 2 * DD, be1 + (size_t)l * 2 * DD, h, M, 2 * DD, DD, 8);
        gemm_kernel<1><<<mt8 * 4, 512, 0, stream>>>(
            h, W2t + (size_t)l * DD * 2 * DD, b2 + (size_t)l * DD,
            nullptr, nullptr, x, M, DD, 2 * DD, 4);
    }
    ln_kernel<<<M, 256, 0, stream>>>(x, lng, lnb, t);
    gemm_kernel<2><<<mt8 * 4, 512, 0, stream>>>(
        t, Wmt, bm, nullptr, nullptr, h, M, DD, DD, 4);
    gemm_kernel<2><<<mt8 * 4, 512, 0, stream>>>(
        h, Wmt + (size_t)DD * DD, bm + DD, nullptr, nullptr, t, M, DD, DD, 4);
    gemm_kernel<2><<<mt8 * 4, 512, 0, stream>>>(
        t, Wmt + (size_t)2 * DD * DD, bm + 2 * DD, nullptr, nullptr, h, M, DD, DD, 4);
    init_out<<<1, 64, 0, stream>>>(out, bout);
    final_reduce<<<dim3(32, BB), 256, 0, stream>>>(h, Wout, out);
}

// Round 11
// 891.657 us; speedup vs baseline: 1.1298x; 1.0546x over previous
//
#include <hip/hip_runtime.h>
#include <hip/hip_fp16.h>

#define BB 4
#define NN 5000
#define KK 4
#define EE 80000
#define DD 512
#define LL 6
#define LMM 3

typedef _Float16 f16x8 __attribute__((ext_vector_type(8)));
typedef _Float16 f16x4 __attribute__((ext_vector_type(4)));
typedef _Float16 f16x2 __attribute__((ext_vector_type(2)));
typedef float f32x4 __attribute__((ext_vector_type(4)));

__device__ __forceinline__ void async_copy16(_Float16* lds, const _Float16* g) {
    __builtin_amdgcn_global_load_lds((const __attribute__((address_space(1))) void*)g,
                                     (__attribute__((address_space(3))) void*)lds,
                                     16, 0, 0);
}

// ---------------- CSR build ----------------
__global__ void zero_int2(int* a, int* b, int n) {
    int i = blockIdx.x * blockDim.x + threadIdx.x;
    if (i < n) { a[i] = 0; b[i] = 0; }
}

__global__ void count_deg(const int* __restrict__ dst, int* __restrict__ deg) {
    int e = blockIdx.x * blockDim.x + threadIdx.x;
    if (e < EE) atomicAdd(&deg[dst[e]], 1);
}

__global__ __launch_bounds__(1024) void scan_off(const int* __restrict__ deg, int* __restrict__ off) {
    __shared__ int s[1024];
    const int n = NN, tot = NN + 1;
    const int per = (tot + 1023) / 1024;   // 5
    int tid = threadIdx.x;
    int start = tid * per;
    int loc[8];
    int sum = 0;
    for (int i = 0; i < per; i++) {
        int idx = start + i;
        int v = (idx < n) ? deg[idx] : 0;
        loc[i] = sum; sum += v;
    }
    s[tid] = sum; __syncthreads();
    for (int o = 1; o < 1024; o <<= 1) {
        int v = (tid >= o) ? s[tid - o] : 0;
        __syncthreads();
        s[tid] += v;
        __syncthreads();
    }
    int base = (tid > 0) ? s[tid - 1] : 0;
    for (int i = 0; i < per; i++) {
        int idx = start + i;
        if (idx < tot) off[idx] = base + loc[i];
    }
}

__global__ void scatter_edges(const int* __restrict__ src, const int* __restrict__ dst,
                              const float* __restrict__ ew, const int* __restrict__ off,
                              int* __restrict__ cursor, int* __restrict__ srcs, float* __restrict__ wss) {
    int e = blockIdx.x * blockDim.x + threadIdx.x;
    if (e >= EE) return;
    int d = dst[e];
    int p = atomicAdd(&cursor[d], 1);
    int idx = off[d] + p;
    srcs[idx] = src[e];
    wss[idx] = ew[e];
}

// ---------------- embedding gather -> f16 ----------------
__global__ __launch_bounds__(256) void embed_kernel(const int* __restrict__ x_idx,
                                                    const float* __restrict__ emb,
                                                    _Float16* __restrict__ x) {
    int row = blockIdx.x;   // b*NN + n
    int d = threadIdx.x * 2;
    int4 iv = *reinterpret_cast<const int4*>(x_idx + (size_t)row * 4);
    float2 a = *reinterpret_cast<const float2*>(emb + (size_t)iv.x * DD + d);
    float2 b = *reinterpret_cast<const float2*>(emb + (size_t)iv.y * DD + d);
    float2 c = *reinterpret_cast<const float2*>(emb + (size_t)iv.z * DD + d);
    float2 e = *reinterpret_cast<const float2*>(emb + (size_t)iv.w * DD + d);
    f16x2 v;
    v[0] = (_Float16)(a.x + b.x + c.x + e.x);
    v[1] = (_Float16)(a.y + b.y + c.y + e.y);
    *reinterpret_cast<f16x2*>(x + (size_t)row * DD + d) = v;
}

// ---------------- GenConv message + softmax-agg + residual ----------------
// EXACT R7 structure (empirical best, 50us): feature-split XCD pinning
// (bid%8 = b*2+h -> 2.56MB gather set per XCD, L2-resident; FETCH 12.6MB
// proven), LDS-staged 64-edge chunks + plain inner loop (compiler keeps
// gathers in flight). R3/R8/R9 restructurings all regressed - do not touch.
__global__ __launch_bounds__(128) void conv_kernel(const _Float16* __restrict__ x,
                                                   const int* __restrict__ srcs,
                                                   const float* __restrict__ wss,
                                                   const int* __restrict__ off,
                                                   _Float16* __restrict__ t) {
    int bh = blockIdx.x;                 // b*2 + h
    int b = bh >> 1, h = bh & 1;
    int wave = threadIdx.x >> 6, lane = threadIdx.x & 63;
    int n = blockIdx.y * 2 + wave;
    const _Float16* xb = x + (size_t)b * NN * DD + h * (DD / 2);
    int e0 = off[n], e1 = off[n + 1];
    __shared__ int   ss[2][64];
    __shared__ float sw[2][64];
    int d0 = lane * 4;
    float S[4] = {0.f, 0.f, 0.f, 0.f};
    float Z[4] = {0.f, 0.f, 0.f, 0.f};
    for (int base = e0; base < e1; base += 64) {
        int cnt = min(64, e1 - base);
        if (lane < cnt) { ss[wave][lane] = srcs[base + lane]; sw[wave][lane] = wss[base + lane]; }
        for (int j = 0; j < cnt; j++) {
            f16x4 xv = *reinterpret_cast<const f16x4*>(xb + (size_t)ss[wave][j] * DD + d0);
            float w = sw[wave][j];
#pragma unroll
            for (int q = 0; q < 4; q++) {
                float m = fmaxf((float)xv[q] + w, 0.f);
                float p = __expf(m);
                S[q] += p;
                Z[q] = fmaf(m, p, Z[q]);
            }
        }
    }
    f16x4 xn = *reinterpret_cast<const f16x4*>(xb + (size_t)n * DD + d0);
    f16x4 o;
#pragma unroll
    for (int q = 0; q < 4; q++) {
        float agg = (e1 > e0) ? (Z[q] / (S[q] + 1e-16f) + 1e-7f) : 0.f;
        o[q] = (_Float16)(agg + (float)xn[q]);
    }
    *reinterpret_cast<f16x4*>(t + ((size_t)b * NN + n) * DD + h * (DD / 2) + d0) = o;
}

// ---------------- weight transpose f32 -> f16 (N-major), all layers per launch --------
__global__ void transpose_f32_f16(const float* __restrict__ W, _Float16* __restrict__ Wt,
                                  int K, int Nc) {
    __shared__ float tile[32][33];
    size_t loff = (size_t)blockIdx.z * K * Nc;
    int n0 = blockIdx.x * 32, k0 = blockIdx.y * 32;
    int tx = threadIdx.x, ty = threadIdx.y;
    for (int i = 0; i < 32; i += 8)
        tile[ty + i][tx] = W[loff + (size_t)(k0 + ty + i) * Nc + n0 + tx];
    __syncthreads();
    for (int i = 0; i < 32; i += 8)
        Wt[loff + (size_t)(n0 + ty + i) * K + k0 + tx] = (_Float16)tile[tx][ty + i];
}

// ---------------- MFMA GEMM: C = A(MxK) * Bt(NxK)^T ----------------
// R7 structure (proven best): 128x128 tile, BK=32 dbuf global_load_lds, one
// barrier per K-iter, XCD-major m-stripes, LDS-transposed f16x8 epilogue.
// NEW: correct bank swizzle sigma(r) = (r>>1)&3. Row stride is 64B = 16
// banks, so bank group = 16*(l16&1) + 4*chunk; even/odd lane parity groups
// each need the 4 chunk slots spread over (l16>>1)&3 -> exactly 2 lanes/bank
// (free, m136). Old sigma(r)=r&3 left even lanes on 2 chunks = 4-way.
// MODE 0: bn+relu  1: bias+relu  2: bias+gelu  (-> f16)
template <int MODE>
__global__ __launch_bounds__(256) void gemm_kernel(const _Float16* __restrict__ A,
                                                   const _Float16* __restrict__ Bt,
                                                   const float* __restrict__ bias,
                                                   const float* __restrict__ g,
                                                   const float* __restrict__ be,
                                                   _Float16* __restrict__ Cout,
                                                   int M, int N, int K, int nt) {
    constexpr int BM = 128, BN = 128, BK = 32;
    constexpr int BUF = (BM + BN) * BK;           // elements per buffer
    __shared__ __align__(16) _Float16 smem[2 * BUF];  // 32 KB
    int tid = threadIdx.x;
    int bid = blockIdx.x;
    int xcd = bid & 7, gidx = bid >> 3;
    int m0 = (xcd + 8 * (gidx / nt)) * BM;
    int n0 = (gidx % nt) * BN;
    int lane = tid & 63, wave = tid >> 6;
    int wm = (wave & 1) * 64, wn = (wave >> 1) * 64;
    int l16 = lane & 15, quad = lane >> 4;
    // staging: row r = tid>>2 (and +64), chunk slot tid&3 holds global chunk
    // (tid&3) ^ sigma(r) with sigma(r) = (r>>1)&3
    int r0 = tid >> 2, r1 = r0 + 64;
    int c0s = ((tid & 3) ^ ((r0 >> 1) & 3)) * 8;
    int c1s = ((tid & 3) ^ ((r1 >> 1) & 3)) * 8;
    const _Float16* pa0 = A + (size_t)min(m0 + r0, M - 1) * K + c0s;
    const _Float16* pa1 = A + (size_t)min(m0 + r1, M - 1) * K + c1s;
    const _Float16* pb0 = Bt + (size_t)(n0 + r0) * K + c0s;
    const _Float16* pb1 = Bt + (size_t)(n0 + r1) * K + c1s;
    int la0 = tid * 8, la1 = (tid + 256) * 8;     // A slot offsets within buffer
    int lb0 = BM * BK + la0, lb1 = BM * BK + la1; // B slot offsets within buffer

    f32x4 acc[4][4] = {};
    // prologue: stage tile 0 into buffer 0
    async_copy16(smem + la0, pa0);
    async_copy16(smem + la1, pa1);
    async_copy16(smem + lb0, pb0);
    async_copy16(smem + lb1, pb1);
    int buf = 0;
    // reader: global chunk `quad` of row (wm+i*16+l16) lives at slot
    // quad ^ sigma(row); sigma(row) = (l16>>1)&3 since wm+i*16 is mult of 16
    int qa = (quad ^ ((l16 >> 1) & 3)) * 8;
    for (int k0 = 0; k0 < K; k0 += BK, buf ^= BUF) {
        __syncthreads();                       // drains buf loads; frees other buffer
        int kn = k0 + BK;
        int nb = buf ^ BUF;
        if (kn < K) {                          // issue next tile AFTER the barrier
            async_copy16(smem + nb + la0, pa0 + kn);
            async_copy16(smem + nb + la1, pa1 + kn);
            async_copy16(smem + nb + lb0, pb0 + kn);
            async_copy16(smem + nb + lb1, pb1 + kn);
        }
        f16x8 af[4], bf[4];
#pragma unroll
        for (int i = 0; i < 4; i++)
            af[i] = *reinterpret_cast<const f16x8*>(&smem[buf + (wm + i * 16 + l16) * BK + qa]);
#pragma unroll
        for (int j = 0; j < 4; j++)
            bf[j] = *reinterpret_cast<const f16x8*>(&smem[buf + BM * BK + (wn + j * 16 + l16) * BK + qa]);
#pragma unroll
        for (int i = 0; i < 4; i++)
#pragma unroll
            for (int j = 0; j < 4; j++)
                acc[i][j] = __builtin_amdgcn_mfma_f32_16x16x32_f16(af[i], bf[j], acc[i][j], 0, 0, 0);
    }
    __syncthreads();
    // epilogue: per 64-col phase, owning waves write Ct[128][64] to LDS, then
    // all 256 threads store f16x8 full sectors (no write-allocate RFO)
    const float invs = rsqrtf(1.0f + 1e-5f);
    _Float16* Ct = smem;
#pragma unroll
    for (int p = 0; p < 2; p++) {
        if ((wave >> 1) == p) {
#pragma unroll
            for (int i = 0; i < 4; i++) {
#pragma unroll
                for (int j = 0; j < 4; j++) {
                    int col = n0 + wn + j * 16 + l16;
#pragma unroll
                    for (int r = 0; r < 4; r++) {
                        float v = acc[i][j][r] + bias[col];
                        if (MODE == 0) {
                            v = fmaxf(v * (g[col] * invs) + be[col], 0.f);
                        } else if (MODE == 1) {
                            v = fmaxf(v, 0.f);
                        } else {
                            v = 0.5f * v * (1.0f + erff(v * 0.70710678118654752f));
                        }
                        Ct[(wm + i * 16 + quad * 4 + r) * 64 + j * 16 + l16] = (_Float16)v;
                    }
                }
            }
        }
        __syncthreads();
#pragma unroll
        for (int k = 0; k < 4; k++) {
            int ch = tid + 256 * k;
            int row = ch >> 3, cc = (ch & 7) * 8;
            int grow = m0 + row;
            if (grow < M)
                *reinterpret_cast<f16x8*>(Cout + (size_t)grow * N + n0 + p * 64 + cc) =
                    *reinterpret_cast<const f16x8*>(&Ct[row * 64 + cc]);
        }
        __syncthreads();
    }
}

// ---------------- LayerNorm (f16 in/out) ----------------
__device__ __forceinline__ float block_sum_256(float v, volatile float* sbuf) {
    __syncthreads();
    for (int s = 32; s; s >>= 1) v += __shfl_down(v, s);
    int wv = threadIdx.x >> 6, ln = threadIdx.x & 63;
    if (ln == 0) sbuf[wv] = v;
    __syncthreads();
    if (threadIdx.x == 0) sbuf[4] = sbuf[0] + sbuf[1] + sbuf[2] + sbuf[3];
    __syncthreads();
    return sbuf[4];
}

__global__ __launch_bounds__(256) void ln_kernel(const _Float16* __restrict__ x,
                                                 const float* __restrict__ lg,
                                                 const float* __restrict__ lb,
                                                 _Float16* __restrict__ t) {
    __shared__ float sbuf[5];
    size_t row = blockIdx.x;
    int d = threadIdx.x * 2;
    f16x2 xv = *reinterpret_cast<const f16x2*>(x + row * DD + d);
    float v0 = (float)xv[0], v1 = (float)xv[1];
    float mu = block_sum_256(v0 + v1, sbuf) * (1.0f / DD);
    float d0 = v0 - mu, d1 = v1 - mu;
    float var = block_sum_256(d0 * d0 + d1 * d1, sbuf) * (1.0f / DD);
    float rs = rsqrtf(var + 1e-5f);
    f16x2 o;
    o[0] = (_Float16)(d0 * rs * lg[d] + lb[d]);
    o[1] = (_Float16)(d1 * rs * lg[d + 1] + lb[d + 1]);
    *reinterpret_cast<f16x2*>(t + row * DD + d) = o;
}

// ---------------- final projection + mean ----------------
__global__ void init_out(float* out, const float* __restrict__ bout) {
    if (threadIdx.x < BB) out[threadIdx.x] = bout[0];
}

__global__ __launch_bounds__(256) void final_reduce(const _Float16* __restrict__ h,
                                                    const float* __restrict__ wout,
                                                    float* __restrict__ out) {
    int b = blockIdx.y;
    const _Float16* hb = h + (size_t)b * NN * DD;
    int lane = threadIdx.x & 63, wave = threadIdx.x >> 6;
    float wv[8];
#pragma unroll
    for (int j = 0; j < 8; j++) wv[j] = wout[lane * 8 + j];
    float acc = 0.f;
    for (int n = blockIdx.x * 4 + wave; n < NN; n += gridDim.x * 4) {
        f16x8 hv = *reinterpret_cast<const f16x8*>(hb + (size_t)n * DD + lane * 8);
#pragma unroll
        for (int j = 0; j < 8; j++) acc += (float)hv[j] * wv[j];
    }
    for (int s = 32; s; s >>= 1) acc += __shfl_down(acc, s);
    __shared__ float sb[4];
    if (lane == 0) sb[wave] = acc;
    __syncthreads();
    if (threadIdx.x == 0) atomicAdd(&out[b], (sb[0] + sb[1] + sb[2] + sb[3]) * (1.0f / NN));
}

extern "C" void kernel_launch(void* const* d_in, const int* in_sizes, int n_in,
                              void* d_out, int out_size, void* d_ws, size_t ws_size,
                              hipStream_t stream) {
    const int*   x_idx = (const int*)d_in[0];
    const int*   eidx  = (const int*)d_in[1];
    const float* ew    = (const float*)d_in[2];
    const float* emb   = (const float*)d_in[3];
    const float* W1    = (const float*)d_in[4];
    const float* b1    = (const float*)d_in[5];
    const float* g1    = (const float*)d_in[6];
    const float* be1   = (const float*)d_in[7];
    const float* W2    = (const float*)d_in[8];
    const float* b2    = (const float*)d_in[9];
    const float* lng   = (const float*)d_in[10];
    const float* lnb   = (const float*)d_in[11];
    const float* Wm    = (const float*)d_in[12];
    const float* bm    = (const float*)d_in[13];
    const float* Wout  = (const float*)d_in[14];
    const float* bout  = (const float*)d_in[15];
    float* out = (float*)d_out;

    char* w = (char*)d_ws;
    size_t o = 0;
    auto alloc = [&](size_t bytes) -> void* {
        void* p = w + o;
        o = (o + bytes + 255) & ~(size_t)255;
        return p;
    };
    _Float16*  x    = (_Float16*)alloc((size_t)BB * NN * DD * 2);
    _Float16*  t    = (_Float16*)alloc((size_t)BB * NN * DD * 2);
    _Float16*  h    = (_Float16*)alloc((size_t)BB * NN * 2 * DD * 2);
    _Float16*  W1t  = (_Float16*)alloc((size_t)LL * 2 * DD * DD * 2);
    _Float16*  W2t  = (_Float16*)alloc((size_t)LL * DD * 2 * DD * 2);
    _Float16*  Wmt  = (_Float16*)alloc((size_t)LMM * DD * DD * 2);
    int*    deg    = (int*)alloc((size_t)NN * 4);
    int*    offs   = (int*)alloc((size_t)(NN + 1) * 4);
    int*    cursor = (int*)alloc((size_t)NN * 4);
    int*    srcs   = (int*)alloc((size_t)EE * 4);
    float*  wss    = (float*)alloc((size_t)EE * 4);

    const int* src = eidx;
    const int* dst = eidx + EE;

    zero_int2<<<(NN + 255) / 256, 256, 0, stream>>>(deg, cursor, NN);
    count_deg<<<(EE + 255) / 256, 256, 0, stream>>>(dst, deg);
    scan_off<<<1, 1024, 0, stream>>>(deg, offs);
    scatter_edges<<<(EE + 255) / 256, 256, 0, stream>>>(src, dst, ew, offs, cursor, srcs, wss);
    embed_kernel<<<BB * NN, 256, 0, stream>>>(x_idx, emb, x);

    transpose_f32_f16<<<dim3(2 * DD / 32, DD / 32, LL), dim3(32, 8), 0, stream>>>(W1, W1t, DD, 2 * DD);
    transpose_f32_f16<<<dim3(DD / 32, 2 * DD / 32, LL), dim3(32, 8), 0, stream>>>(W2, W2t, 2 * DD, DD);
    transpose_f32_f16<<<dim3(DD / 32, DD / 32, LMM), dim3(32, 8), 0, stream>>>(Wm, Wmt, DD, DD);

    const int M = BB * NN;
    const int mt8 = ((M + 127) / 128 + 7) & ~7;   // 160 m-tiles, multiple of 8
    for (int l = 0; l < LL; l++) {
        conv_kernel<<<dim3(2 * BB, NN / 2), 128, 0, stream>>>(x, srcs, wss, offs, t);
        gemm_kernel<0><<<mt8 * 8, 256, 0, stream>>>(
            t, W1t + (size_t)l * 2 * DD * DD, b1 + (size_t)l * 2 * DD,
            g1 + (size_t)l * 2 * DD, be1 + (size_t)l * 2 * DD, h, M, 2 * DD, DD, 8);
        gemm_kernel<1><<<mt8 * 4, 256, 0, stream>>>(
            h, W2t + (size_t)l * DD * 2 * DD, b2 + (size_t)l * DD,
            nullptr, nullptr, x, M, DD, 2 * DD, 4);
    }
    ln_kernel<<<M, 256, 0, stream>>>(x, lng, lnb, t);
    gemm_kernel<2><<<mt8 * 4, 256, 0, stream>>>(
        t, Wmt, bm, nullptr, nullptr, h, M, DD, DD, 4);
    gemm_kernel<2><<<mt8 * 4, 256, 0, stream>>>(
        h, Wmt + (size_t)DD * DD, bm + DD, nullptr, nullptr, t, M, DD, DD, 4);
    gemm_kernel<2><<<mt8 * 4, 256, 0, stream>>>(
        t, Wmt + (size_t)2 * DD * DD, bm + 2 * DD, nullptr, nullptr, h, M, DD, DD, 4);
    init_out<<<1, 64, 0, stream>>>(out, bout);
    final_reduce<<<dim3(32, BB), 256, 0, stream>>>(h, Wout, out);
}